// Round 2
// baseline (10194.973 us; speedup 1.0000x reference)
//
#include <hip/hip_runtime.h>
#include <type_traits>

// ---------------- types ----------------
typedef _Float16 half8 __attribute__((ext_vector_type(8)));
typedef _Float16 half4v __attribute__((ext_vector_type(4)));
typedef float f32x4 __attribute__((ext_vector_type(4)));
typedef unsigned long long u64;

struct U128 { u64 a, b; };

#define B_ 64
#define T_ 512
#define H_ 1024
#define G_ 4096      // 4*H
#define K_ 1024
#define MPROJ (B_ * T_)  // 32768

// ---------------- prep kernels ----------------
__global__ void k_f32_to_f16(const float* __restrict__ s, _Float16* __restrict__ d, int n4) {
  int i = blockIdx.x * 256 + threadIdx.x;
  if (i < n4) {
    float4 v = ((const float4*)s)[i];
    half4v o;
    o[0] = (_Float16)v.x; o[1] = (_Float16)v.y; o[2] = (_Float16)v.z; o[3] = (_Float16)v.w;
    ((half4v*)d)[i] = o;
  }
}

__global__ void k_bias(const float* __restrict__ bi0, const float* __restrict__ bh0,
                       const float* __restrict__ bi1, const float* __restrict__ bh1,
                       float* __restrict__ o0, float* __restrict__ o1) {
  int i = blockIdx.x * 256 + threadIdx.x;
  if (i < G_) { o0[i] = bi0[i] + bh0[i]; o1[i] = bi1[i] + bh1[i]; }
}

__global__ void k_zero(uint4* __restrict__ p, int n) {
  int i = blockIdx.x * 256 + threadIdx.x;
  if (i < n) p[i] = make_uint4(0u, 0u, 0u, 0u);
}

// ---------------- projection GEMM ----------------
// C[m][n] = sum_k A[m][k]*Bw[n][k] + bias[n], C stored fp16. M=32768, N=4096, K=1024.
// 128x128 tile, BK=32, 256 thr (4 waves, each a 64x64 quadrant of 4x4 16x16x32 MFMAs).
template <typename AT>
__global__ __launch_bounds__(256, 2) void k_proj(const AT* __restrict__ A,
                                                 const _Float16* __restrict__ Bw,
                                                 const float* __restrict__ bias,
                                                 _Float16* __restrict__ C) {
  const int NBN = G_ / 128;  // 32
  int bm = blockIdx.x / NBN;
  int bn = blockIdx.x % NBN;
  __shared__ __align__(16) _Float16 As[128 * 40];
  __shared__ __align__(16) _Float16 Bs[128 * 40];
  int tid = threadIdx.x;
  int lane = tid & 63, wave = tid >> 6;
  int wm = (wave >> 1) * 64, wn = (wave & 1) * 64;
  int quad = lane >> 4, l16 = lane & 15;
  f32x4 acc[4][4] = {};
  int r = tid >> 1;            // staged row 0..127
  int hc = (tid & 1) * 16;     // half-offset within BK=32
  const AT* aRow = A + (size_t)(bm * 128 + r) * K_ + hc;
  const _Float16* bRow = Bw + (size_t)(bn * 128 + r) * K_ + hc;
  _Float16* aDst = As + r * 40 + hc;
  _Float16* bDst = Bs + r * 40 + hc;

  for (int kt = 0; kt < K_ / 32; ++kt) {
    if constexpr (std::is_same<AT, float>::value) {
      float tmp[16];
      *(float4*)(tmp + 0)  = *(const float4*)(aRow + 0);
      *(float4*)(tmp + 4)  = *(const float4*)(aRow + 4);
      *(float4*)(tmp + 8)  = *(const float4*)(aRow + 8);
      *(float4*)(tmp + 12) = *(const float4*)(aRow + 12);
      half8 h0, h1;
#pragma unroll
      for (int e = 0; e < 8; ++e) { h0[e] = (_Float16)tmp[e]; h1[e] = (_Float16)tmp[e + 8]; }
      *(half8*)(aDst) = h0;
      *(half8*)(aDst + 8) = h1;
    } else {
      *(half8*)(aDst) = *(const half8*)(aRow);
      *(half8*)(aDst + 8) = *(const half8*)(aRow + 8);
    }
    *(half8*)(bDst) = *(const half8*)(bRow);
    *(half8*)(bDst + 8) = *(const half8*)(bRow + 8);
    __syncthreads();
    half8 af[4], bf[4];
#pragma unroll
    for (int i = 0; i < 4; ++i) af[i] = *(const half8*)(As + (wm + i * 16 + l16) * 40 + quad * 8);
#pragma unroll
    for (int j = 0; j < 4; ++j) bf[j] = *(const half8*)(Bs + (wn + j * 16 + l16) * 40 + quad * 8);
#pragma unroll
    for (int i = 0; i < 4; ++i)
#pragma unroll
      for (int j = 0; j < 4; ++j)
        acc[i][j] = __builtin_amdgcn_mfma_f32_16x16x32_f16(af[i], bf[j], acc[i][j], 0, 0, 0);
    __syncthreads();
    aRow += 32;
    bRow += 32;
  }
  // epilogue: C/D layout m = quad*4+reg, n = lane&15
#pragma unroll
  for (int j = 0; j < 4; ++j) {
    int n = bn * 128 + wn + j * 16 + l16;
    float bv = bias[n];
#pragma unroll
    for (int i = 0; i < 4; ++i) {
      size_t m0 = (size_t)(bm * 128 + wm + i * 16 + quad * 4);
#pragma unroll
      for (int rr = 0; rr < 4; ++rr)
        C[(m0 + rr) * G_ + n] = (_Float16)(acc[i][j][rr] + bv);
    }
  }
}

// ---------------- persistent recurrence ----------------
// 256 WGs x 512 thr (cooperative). Group g = blockIdx&3 owns batch rows [16g,16g+16),
// WG wid = blockIdx>>2 owns hidden units [16*wid,16*wid+16) (all 4 gates).
// W_hh slice in registers (K split 8-ways over waves). c state in LDS.
//
// Sync protocol (v3): SELF-FLAGGING TAGGED DATA — one MALL round trip per step.
//  - h exchanged as 32-bit words {tag:16, h_fp16:16}; tag = producing step + 1.
//    Zero-init == tag 0 == the h_{-1}=0 initial state.
//  - producer: finalize -> tagged dword stores (agent scope). No drain, no flag.
//  - consumer at step s wants tag==s in buffer (s&1). Poll: 1 sentinel word per
//    32-unit chunk (4 dwords/lane, cheap retries); then full tagged load; VERIFY
//    ALL 32 tags (correctness never relies on store arrival order); rare fail -> retry.
//  - exact-tag spin is deadlock-free: WG q can only overwrite buffer A (step s+1's
//    store) after its step-(s+1) sync#1, which needs h(s) from ALL 64 WGs (producer
//    union), which needs every WG's step-s sync#2, which needs every step-s read of
//    A to have completed. So a reader wanting tag s can never see s+2.
__global__ __launch_bounds__(512, 2) void k_rec(
    const _Float16* __restrict__ xg,   // [B*T][4H] fp16, includes both biases
    const _Float16* __restrict__ Whh,  // [4H][H] fp16
    unsigned* __restrict__ hb0, unsigned* __restrict__ hb1,  // tagged [B][H] ping-pong
    _Float16* __restrict__ out16,      // layer0: out0 buffer; layer1: null
    float* __restrict__ out32,         // layer1: d_out; layer0: null
    float* __restrict__ hn_out, float* __restrict__ cn_out) {
  int g = blockIdx.x & 3;
  int wid = blockIdx.x >> 2;
  int u0 = wid * 16;
  int b0 = g * 16;
  int tid = threadIdx.x;
  int lane = tid & 63, w = tid >> 6;
  int quad = lane >> 4, l16 = lane & 15;

  // m-stride padded to 18 floats: all access phases are <=2-way bank aliased (free)
  __shared__ float part[8][4][16][18];  // [wave][gate][m][n]
  __shared__ float red[4][16][18];      // reduced gates
  __shared__ float cs[16][16];          // cell state
  if (tid < 256) ((float*)cs)[tid] = 0.f;

  // resident W_hh fragments: wave w covers K-slice [128w, 128w+128)
  int ks = w * 128;
  half8 wf[4][4];
#pragma unroll
  for (int gt = 0; gt < 4; ++gt)
#pragma unroll
    for (int kk = 0; kk < 4; ++kk)
      wf[gt][kk] = *(const half8*)(Whh + (size_t)(gt * H_ + u0 + l16) * K_ + ks + kk * 32 + quad * 8);
  int fm = (w & 3) * 4 + quad;
  __syncthreads();

  for (int s = 0; s < T_; ++s) {
    const unsigned* hpT = (s & 1) ? hb1 : hb0;
    unsigned* hnT = (s & 1) ? hb0 : hb1;
    unsigned want = (unsigned)s;

    // xg prefetch issued BEFORE the poll: HBM latency hides under the spin
    float pxi = 0.f, pxf = 0.f, pxg = 0.f, pxo = 0.f;
    if (w < 4) {
      const _Float16* xr = xg + ((size_t)(b0 + fm) * T_ + s) * G_ + u0 + l16;
      pxi = (float)xr[0];
      pxf = (float)xr[H_];
      pxg = (float)xr[2 * H_];
      pxo = (float)xr[3 * H_];
    }

    // this lane's 4 tagged 8-dword runs start here (one per 32-unit chunk)
    const unsigned* rowp = hpT + (size_t)(b0 + l16) * H_ + ks + quad * 8;

    // --- sentinel poll: last word of each run (1 KB/wave per retry) ---
    for (;;) {
      unsigned t0 = __hip_atomic_load(rowp + 0 * 32 + 7, __ATOMIC_RELAXED, __HIP_MEMORY_SCOPE_AGENT);
      unsigned t1 = __hip_atomic_load(rowp + 1 * 32 + 7, __ATOMIC_RELAXED, __HIP_MEMORY_SCOPE_AGENT);
      unsigned t2 = __hip_atomic_load(rowp + 2 * 32 + 7, __ATOMIC_RELAXED, __HIP_MEMORY_SCOPE_AGENT);
      unsigned t3 = __hip_atomic_load(rowp + 3 * 32 + 7, __ATOMIC_RELAXED, __HIP_MEMORY_SCOPE_AGENT);
      unsigned bad = ((t0 >> 16) ^ want) | ((t1 >> 16) ^ want) |
                     ((t2 >> 16) ^ want) | ((t3 >> 16) ^ want);
      if (__all(bad == 0)) break;
      __builtin_amdgcn_s_sleep(1);
    }
    asm volatile("" ::: "memory");  // keep full loads below the sentinel pass

    // --- full tagged load + verify ALL tags + pack to fp16 fragments ---
    half8 af[4];
    for (;;) {
      u64 r0[4], r1[4], r2[4], r3[4];
#pragma unroll
      for (int j = 0; j < 4; ++j) {
        r0[j] = __hip_atomic_load((const u64*)(rowp + 0 * 32) + j, __ATOMIC_RELAXED, __HIP_MEMORY_SCOPE_AGENT);
        r1[j] = __hip_atomic_load((const u64*)(rowp + 1 * 32) + j, __ATOMIC_RELAXED, __HIP_MEMORY_SCOPE_AGENT);
        r2[j] = __hip_atomic_load((const u64*)(rowp + 2 * 32) + j, __ATOMIC_RELAXED, __HIP_MEMORY_SCOPE_AGENT);
        r3[j] = __hip_atomic_load((const u64*)(rowp + 3 * 32) + j, __ATOMIC_RELAXED, __HIP_MEMORY_SCOPE_AGENT);
      }
      unsigned bad = 0;
#pragma unroll
      for (int j = 0; j < 4; ++j) {
        bad |= ((((unsigned)(r0[j] >> 16)) & 0xFFFFu) ^ want) | (((unsigned)(r0[j] >> 48)) ^ want);
        bad |= ((((unsigned)(r1[j] >> 16)) & 0xFFFFu) ^ want) | (((unsigned)(r1[j] >> 48)) ^ want);
        bad |= ((((unsigned)(r2[j] >> 16)) & 0xFFFFu) ^ want) | (((unsigned)(r2[j] >> 48)) ^ want);
        bad |= ((((unsigned)(r3[j] >> 16)) & 0xFFFFu) ^ want) | (((unsigned)(r3[j] >> 48)) ^ want);
      }
      if (__all(bad == 0)) {
        u64 rr[4][4];
#pragma unroll
        for (int j = 0; j < 4; ++j) { rr[0][j] = r0[j]; rr[1][j] = r1[j]; rr[2][j] = r2[j]; rr[3][j] = r3[j]; }
#pragma unroll
        for (int kk = 0; kk < 4; ++kk) {
          unsigned d0 = ((unsigned)rr[kk][0] & 0xFFFFu) | (((unsigned)(rr[kk][0] >> 32)) << 16);
          unsigned d1 = ((unsigned)rr[kk][1] & 0xFFFFu) | (((unsigned)(rr[kk][1] >> 32)) << 16);
          unsigned d2 = ((unsigned)rr[kk][2] & 0xFFFFu) | (((unsigned)(rr[kk][2] >> 32)) << 16);
          unsigned d3 = ((unsigned)rr[kk][3] & 0xFFFFu) | (((unsigned)(rr[kk][3] >> 32)) << 16);
          U128 u;
          u.a = (u64)d0 | ((u64)d1 << 32);
          u.b = (u64)d2 | ((u64)d3 << 32);
          af[kk] = __builtin_bit_cast(half8, u);
        }
        break;
      }
      __builtin_amdgcn_s_sleep(1);
    }

    f32x4 acc[4] = {};
#pragma unroll
    for (int kk = 0; kk < 4; ++kk)
#pragma unroll
      for (int gt = 0; gt < 4; ++gt)
        acc[gt] = __builtin_amdgcn_mfma_f32_16x16x32_f16(af[kk], wf[gt][kk], acc[gt], 0, 0, 0);
#pragma unroll
    for (int gt = 0; gt < 4; ++gt)
#pragma unroll
      for (int rr = 0; rr < 4; ++rr)
        part[w][gt][quad * 4 + rr][l16] = acc[gt][rr];
    __syncthreads();  // sync#1: join for reduce

    {  // cross-wave K reduction: wave w -> gate w&3, row-half w>>2
      int gt = w & 3, rh = w >> 2;
#pragma unroll
      for (int rr = 2 * rh; rr < 2 * rh + 2; ++rr) {
        int m = quad * 4 + rr;
        float sum = part[0][gt][m][l16];
#pragma unroll
        for (int w2 = 1; w2 < 8; ++w2) sum += part[w2][gt][m][l16];
        red[gt][m][l16] = sum;
      }
    }
    __syncthreads();  // sync#2: red ready; all waves' h reads for this step complete

    if (w < 4) {  // finalization: 4 waves x 64 lanes = 256 (m,n) cells
      int m = fm, n = l16;
      float iv = red[0][m][n] + pxi;
      float fv = red[1][m][n] + pxf;
      float gv = red[2][m][n] + pxg;
      float ov = red[3][m][n] + pxo;
      float si = 1.f / (1.f + __expf(-iv));
      float sf = 1.f / (1.f + __expf(-fv));
      float so = 1.f / (1.f + __expf(-ov));
      float ag = fabsf(gv), eg = __expf(-2.f * ag);
      float tg = (1.f - eg) / (1.f + eg);
      tg = (gv < 0.f) ? -tg : tg;
      float c = sf * cs[m][n] + si * tg;
      float ac = fabsf(c), ec = __expf(-2.f * ac);
      float th = (1.f - ec) / (1.f + ec);
      th = (c < 0.f) ? -th : th;
      float h = so * th;
      // tagged h store: {tag=s+1, h_fp16}. Single dword, word-atomic -> self-flagging.
      unsigned short hu = __builtin_bit_cast(unsigned short, (_Float16)h);
      unsigned packed = ((unsigned)(s + 1) << 16) | (unsigned)hu;
      __hip_atomic_store(hnT + (size_t)(b0 + m) * H_ + u0 + n, packed,
                         __ATOMIC_RELAXED, __HIP_MEMORY_SCOPE_AGENT);
      // ---- off the critical path ----
      cs[m][n] = c;
      size_t oidx = ((size_t)(b0 + m) * T_ + s) * H_ + u0 + n;
      if (out16) out16[oidx] = (_Float16)h;
      if (out32) out32[oidx] = h;
      if (s == T_ - 1) {
        hn_out[(size_t)(b0 + m) * H_ + u0 + n] = h;
        cn_out[(size_t)(b0 + m) * H_ + u0 + n] = c;
      }
    }
    // no third barrier: waves free-run into the next round's poll;
    // part[]/red reuse is protected by sync#2 (this step) + sync#1 (next step).
  }
}

// ---------------- host ----------------
extern "C" void kernel_launch(void* const* d_in, const int* in_sizes, int n_in,
                              void* d_out, int out_size, void* d_ws, size_t ws_size,
                              hipStream_t stream) {
  (void)in_sizes; (void)n_in; (void)out_size;
  const float* X    = (const float*)d_in[0];
  const float* Wih0 = (const float*)d_in[1];
  const float* bih0 = (const float*)d_in[2];
  const float* Whh0 = (const float*)d_in[3];
  const float* bhh0 = (const float*)d_in[4];
  const float* Wih1 = (const float*)d_in[5];
  const float* bih1 = (const float*)d_in[6];
  const float* Whh1 = (const float*)d_in[7];
  const float* bhh1 = (const float*)d_in[8];
  float* out = (float*)d_out;
  char* ws = (char*)d_ws;

  // ws layout (bytes):
  constexpr size_t SZW = (size_t)G_ * K_ * 2;  // 8 MB per packed weight
  constexpr size_t OFF_B0   = 4 * SZW;
  constexpr size_t OFF_B1   = OFF_B0 + 16384;
  constexpr size_t OFF_HBUF = OFF_B1 + 16384;          // 4 tagged buffers x 256 KB
  constexpr size_t SZHB     = (size_t)B_ * H_ * 4;     // 256 KB
  constexpr size_t OFF_OUT0 = OFF_HBUF + 4 * SZHB;
  constexpr size_t OFF_XG   = OFF_OUT0 + (size_t)MPROJ * H_ * 2;
  constexpr size_t NEED     = OFF_XG + (size_t)MPROJ * G_ * 2;
  if (ws_size < NEED) return;  // fail visibly rather than corrupt

  _Float16* Wih0h = (_Float16*)(ws + 0 * SZW);
  _Float16* Whh0h = (_Float16*)(ws + 1 * SZW);
  _Float16* Wih1h = (_Float16*)(ws + 2 * SZW);
  _Float16* Whh1h = (_Float16*)(ws + 3 * SZW);
  float* b0s = (float*)(ws + OFF_B0);
  float* b1s = (float*)(ws + OFF_B1);
  unsigned* hb00 = (unsigned*)(ws + OFF_HBUF);
  unsigned* hb01 = hb00 + B_ * H_;
  unsigned* hb10 = hb01 + B_ * H_;
  unsigned* hb11 = hb10 + B_ * H_;
  _Float16* out0h = (_Float16*)(ws + OFF_OUT0);
  _Float16* xgp   = (_Float16*)(ws + OFF_XG);

  // prep: pack weights to fp16, fold biases, zero tagged h buffers (tag 0 = h_{-1}=0)
  k_f32_to_f16<<<4096, 256, 0, stream>>>(Wih0, Wih0h, G_ * K_ / 4);
  k_f32_to_f16<<<4096, 256, 0, stream>>>(Whh0, Whh0h, G_ * K_ / 4);
  k_f32_to_f16<<<4096, 256, 0, stream>>>(Wih1, Wih1h, G_ * K_ / 4);
  k_f32_to_f16<<<4096, 256, 0, stream>>>(Whh1, Whh1h, G_ * K_ / 4);
  k_bias<<<16, 256, 0, stream>>>(bih0, bhh0, bih1, bhh1, b0s, b1s);
  k_zero<<<256, 256, 0, stream>>>((uint4*)(ws + OFF_HBUF), (int)(4 * SZHB / 16));

  const int projGrid = (MPROJ / 128) * (G_ / 128);  // 8192

  // layer 0
  k_proj<float><<<dim3(projGrid), dim3(256), 0, stream>>>(X, Wih0h, b0s, xgp);
  {
    const _Float16* a0 = xgp;
    const _Float16* a1 = Whh0h;
    unsigned* a2 = hb00;
    unsigned* a3 = hb01;
    _Float16* a4 = out0h;
    float* a5 = nullptr;
    float* a6 = out + 33554432;            // h_n[0]
    float* a7 = out + 33554432 + 131072;   // c_n[0]
    void* args[8] = {&a0, &a1, &a2, &a3, &a4, &a5, &a6, &a7};
    hipLaunchCooperativeKernel((void*)k_rec, dim3(256), dim3(512), args, 0, stream);
  }

  // layer 1
  k_proj<_Float16><<<dim3(projGrid), dim3(256), 0, stream>>>(out0h, Wih1h, b1s, xgp);
  {
    const _Float16* a0 = xgp;
    const _Float16* a1 = Whh1h;
    unsigned* a2 = hb10;
    unsigned* a3 = hb11;
    _Float16* a4 = nullptr;
    float* a5 = out;                               // out1
    float* a6 = out + 33554432 + 65536;            // h_n[1]
    float* a7 = out + 33554432 + 131072 + 65536;   // c_n[1]
    void* args[8] = {&a0, &a1, &a2, &a3, &a4, &a5, &a6, &a7};
    hipLaunchCooperativeKernel((void*)k_rec, dim3(256), dim3(512), args, 0, stream);
  }
}

// Round 3
// 5036.605 us; speedup vs baseline: 2.0242x; 2.0242x over previous
//
#include <hip/hip_runtime.h>
#include <type_traits>

// ---------------- types ----------------
typedef _Float16 half8 __attribute__((ext_vector_type(8)));
typedef _Float16 half4v __attribute__((ext_vector_type(4)));
typedef float f32x4 __attribute__((ext_vector_type(4)));
typedef unsigned long long u64;

struct U128 { u64 a, b; };

#define B_ 64
#define T_ 512
#define H_ 1024
#define G_ 4096      // 4*H
#define K_ 1024
#define MPROJ (B_ * T_)  // 32768

// ---------------- prep kernels ----------------
__global__ void k_f32_to_f16(const float* __restrict__ s, _Float16* __restrict__ d, int n4) {
  int i = blockIdx.x * 256 + threadIdx.x;
  if (i < n4) {
    float4 v = ((const float4*)s)[i];
    half4v o;
    o[0] = (_Float16)v.x; o[1] = (_Float16)v.y; o[2] = (_Float16)v.z; o[3] = (_Float16)v.w;
    ((half4v*)d)[i] = o;
  }
}

__global__ void k_bias(const float* __restrict__ bi0, const float* __restrict__ bh0,
                       const float* __restrict__ bi1, const float* __restrict__ bh1,
                       float* __restrict__ o0, float* __restrict__ o1) {
  int i = blockIdx.x * 256 + threadIdx.x;
  if (i < G_) { o0[i] = bi0[i] + bh0[i]; o1[i] = bi1[i] + bh1[i]; }
}

__global__ void k_zero(uint4* __restrict__ p, int n) {
  int i = blockIdx.x * 256 + threadIdx.x;
  if (i < n) p[i] = make_uint4(0u, 0u, 0u, 0u);
}

// ---------------- projection GEMM (layer 0 only now) ----------------
// C[m][n] = sum_k A[m][k]*Bw[n][k] + bias[n], C stored fp16. M=32768, N=4096, K=1024.
template <typename AT>
__global__ __launch_bounds__(256, 2) void k_proj(const AT* __restrict__ A,
                                                 const _Float16* __restrict__ Bw,
                                                 const float* __restrict__ bias,
                                                 _Float16* __restrict__ C) {
  const int NBN = G_ / 128;  // 32
  int bm = blockIdx.x / NBN;
  int bn = blockIdx.x % NBN;
  __shared__ __align__(16) _Float16 As[128 * 40];
  __shared__ __align__(16) _Float16 Bs[128 * 40];
  int tid = threadIdx.x;
  int lane = tid & 63, wave = tid >> 6;
  int wm = (wave >> 1) * 64, wn = (wave & 1) * 64;
  int quad = lane >> 4, l16 = lane & 15;
  f32x4 acc[4][4] = {};
  int r = tid >> 1;
  int hc = (tid & 1) * 16;
  const AT* aRow = A + (size_t)(bm * 128 + r) * K_ + hc;
  const _Float16* bRow = Bw + (size_t)(bn * 128 + r) * K_ + hc;
  _Float16* aDst = As + r * 40 + hc;
  _Float16* bDst = Bs + r * 40 + hc;

  for (int kt = 0; kt < K_ / 32; ++kt) {
    if constexpr (std::is_same<AT, float>::value) {
      float tmp[16];
      *(float4*)(tmp + 0)  = *(const float4*)(aRow + 0);
      *(float4*)(tmp + 4)  = *(const float4*)(aRow + 4);
      *(float4*)(tmp + 8)  = *(const float4*)(aRow + 8);
      *(float4*)(tmp + 12) = *(const float4*)(aRow + 12);
      half8 h0, h1;
#pragma unroll
      for (int e = 0; e < 8; ++e) { h0[e] = (_Float16)tmp[e]; h1[e] = (_Float16)tmp[e + 8]; }
      *(half8*)(aDst) = h0;
      *(half8*)(aDst + 8) = h1;
    } else {
      *(half8*)(aDst) = *(const half8*)(aRow);
      *(half8*)(aDst + 8) = *(const half8*)(aRow + 8);
    }
    *(half8*)(bDst) = *(const half8*)(bRow);
    *(half8*)(bDst + 8) = *(const half8*)(bRow + 8);
    __syncthreads();
    half8 af[4], bf[4];
#pragma unroll
    for (int i = 0; i < 4; ++i) af[i] = *(const half8*)(As + (wm + i * 16 + l16) * 40 + quad * 8);
#pragma unroll
    for (int j = 0; j < 4; ++j) bf[j] = *(const half8*)(Bs + (wn + j * 16 + l16) * 40 + quad * 8);
#pragma unroll
    for (int i = 0; i < 4; ++i)
#pragma unroll
      for (int j = 0; j < 4; ++j)
        acc[i][j] = __builtin_amdgcn_mfma_f32_16x16x32_f16(af[i], bf[j], acc[i][j], 0, 0, 0);
    __syncthreads();
    aRow += 32;
    bRow += 32;
  }
#pragma unroll
  for (int j = 0; j < 4; ++j) {
    int n = bn * 128 + wn + j * 16 + l16;
    float bv = bias[n];
#pragma unroll
    for (int i = 0; i < 4; ++i) {
      size_t m0 = (size_t)(bm * 128 + wm + i * 16 + quad * 4);
#pragma unroll
      for (int rr = 0; rr < 4; ++rr)
        C[(m0 + rr) * G_ + n] = (_Float16)(acc[i][j][rr] + bv);
    }
  }
}

// ---------------- fused 2-layer persistent recurrence ----------------
// 256 WGs x 512 thr (cooperative), 1 WG/CU. Group g = blockIdx&3 owns batch rows
// [16g,16g+16); WG wid = blockIdx>>2 owns hidden units [16wid,16wid+16), BOTH layers.
// Iteration i (0..T): layer0 computes step i (i<T), layer1 computes step i-1 (i>=1).
// KEY: layer1's ih-input out0(i-1) == h0(i-1) == the exact fragments (af0) layer0
// loads for its hh-matmul -> one load feeds 3 matmuls. ONE v1-style barrier per
// iteration gates both layers' exchanges: sync rounds 1024 -> 513; proj1 and the
// out0->HBM->xg1 round trip are eliminated.
// Weights/wave: Whh0[4][4] + Whh1[4][4] + Wih1 gates0-1 in regs (160 VGPR);
// Wih1 gates2-3 in LDS (66KB, loop-invariant reads, row pad 1032 -> 2-way max).
__global__ __launch_bounds__(512) void k_fused(
    const _Float16* __restrict__ xg,    // [B*T][4H] fp16 layer0 gates (both biases folded)
    const _Float16* __restrict__ Whh0,  // [4H][H] fp16
    const _Float16* __restrict__ Wih1,  // [4H][H] fp16
    const _Float16* __restrict__ Whh1,  // [4H][H] fp16
    const float* __restrict__ b1,       // [4H] folded layer1 bias
    _Float16* __restrict__ h0a, _Float16* __restrict__ h0b,  // layer0 h ping-pong
    _Float16* __restrict__ h1a, _Float16* __restrict__ h1b,  // layer1 h ping-pong
    unsigned int* cnt_base,             // per-group monotonic counters (64B apart)
    float* __restrict__ out32,          // d_out: out1 [B][T][H] fp32
    float* __restrict__ hn0, float* __restrict__ cn0,
    float* __restrict__ hn1, float* __restrict__ cn1) {
  int g = blockIdx.x & 3;
  int wid = blockIdx.x >> 2;
  int u0 = wid * 16;
  int b0 = g * 16;
  int tid = threadIdx.x;
  int lane = tid & 63, w = tid >> 6;
  int quad = lane >> 4, l16 = lane & 15;
  unsigned int* cnt = cnt_base + g * 16;

  // planes 0-3: layer0 gates; planes 4-7: layer1 gates. m-stride 18 -> <=2-way banks.
  __shared__ float part[8][8][16][18];   // 73728 B
  __shared__ float red[8][16][18];       // 9216 B
  __shared__ float cs[2][16][16];        // 2048 B  (cell states, both layers)
  __shared__ __align__(16) _Float16 wi1_lds[2 * 16 * 1032];  // 66048 B: Wih1 gates 2,3
  __shared__ int step_flag;
  ((float*)cs)[tid] = 0.f;               // tid<512 covers 512 floats exactly
  if (tid == 0) step_flag = 0;

  // stage Wih1 gates 2-3 rows [u0,u0+16) into LDS (one-time)
  for (int idx = tid; idx < 2 * 16 * (K_ / 8); idx += 512) {
    int gt2 = idx >> 11;          // 0..1
    int r = (idx >> 7) & 15;      // 0..15
    int c = idx & 127;            // 0..127 (half8 chunks)
    half8 v = *(const half8*)(Wih1 + (size_t)((2 + gt2) * H_ + u0 + r) * K_ + c * 8);
    *(half8*)(wi1_lds + (gt2 * 16 + r) * 1032 + c * 8) = v;
  }

  // resident weight fragments: wave w covers K-slice [128w, 128w+128)
  int ks = w * 128;
  half8 wf0[4][4], wh1[4][4], wi1r[2][4];
#pragma unroll
  for (int gt = 0; gt < 4; ++gt)
#pragma unroll
    for (int kk = 0; kk < 4; ++kk) {
      wf0[gt][kk] = *(const half8*)(Whh0 + (size_t)(gt * H_ + u0 + l16) * K_ + ks + kk * 32 + quad * 8);
      wh1[gt][kk] = *(const half8*)(Whh1 + (size_t)(gt * H_ + u0 + l16) * K_ + ks + kk * 32 + quad * 8);
    }
#pragma unroll
  for (int gt = 0; gt < 2; ++gt)
#pragma unroll
    for (int kk = 0; kk < 4; ++kk)
      wi1r[gt][kk] = *(const half8*)(Wih1 + (size_t)(gt * H_ + u0 + l16) * K_ + ks + kk * 32 + quad * 8);

  int fm = (w & 3) * 4 + quad;
  float b1v[4] = {};
  if (w >= 4) {
#pragma unroll
    for (int gt = 0; gt < 4; ++gt) b1v[gt] = b1[gt * H_ + u0 + l16];
  }
  __syncthreads();

  for (int i = 0; i <= T_; ++i) {
    const _Float16* h0r = (i & 1) ? h0b : h0a;
    _Float16* h0w = (i & 1) ? h0a : h0b;
    const _Float16* h1r = (i & 1) ? h1b : h1a;
    _Float16* h1w = (i & 1) ? h1a : h1b;

    // layer0 xg prefetch (this iteration's finalize input) — overlaps h loads
    float pxi = 0.f, pxf = 0.f, pxg = 0.f, pxo = 0.f;
    if (w < 4 && i < T_) {
      const _Float16* xr = xg + ((size_t)(b0 + fm) * T_ + i) * G_ + u0 + l16;
      pxi = (float)xr[0];
      pxf = (float)xr[H_];
      pxg = (float)xr[2 * H_];
      pxo = (float)xr[3 * H_];
    }

    // h0(i-1) fragments (feed L0-hh AND L1-ih) and h1(i-2) fragments (L1-hh)
    half8 af0[4], af1[4];
#pragma unroll
    for (int kk = 0; kk < 4; ++kk) {
      const _Float16* hs = h0r + (size_t)(b0 + l16) * H_ + ks + kk * 32 + quad * 8;
      u64 qlo = __hip_atomic_load((const u64*)hs, __ATOMIC_RELAXED, __HIP_MEMORY_SCOPE_AGENT);
      u64 qhi = __hip_atomic_load(((const u64*)hs) + 1, __ATOMIC_RELAXED, __HIP_MEMORY_SCOPE_AGENT);
      U128 u; u.a = qlo; u.b = qhi;
      af0[kk] = __builtin_bit_cast(half8, u);
    }
#pragma unroll
    for (int kk = 0; kk < 4; ++kk) {
      const _Float16* hs = h1r + (size_t)(b0 + l16) * H_ + ks + kk * 32 + quad * 8;
      u64 qlo = __hip_atomic_load((const u64*)hs, __ATOMIC_RELAXED, __HIP_MEMORY_SCOPE_AGENT);
      u64 qhi = __hip_atomic_load(((const u64*)hs) + 1, __ATOMIC_RELAXED, __HIP_MEMORY_SCOPE_AGENT);
      U128 u; u.a = qlo; u.b = qhi;
      af1[kk] = __builtin_bit_cast(half8, u);
    }

    // ---- layer0: acc = af0 x Whh0 ----
    {
      f32x4 acc[4] = {};
#pragma unroll
      for (int kk = 0; kk < 4; ++kk)
#pragma unroll
        for (int gt = 0; gt < 4; ++gt)
          acc[gt] = __builtin_amdgcn_mfma_f32_16x16x32_f16(af0[kk], wf0[gt][kk], acc[gt], 0, 0, 0);
#pragma unroll
      for (int gt = 0; gt < 4; ++gt)
#pragma unroll
        for (int rr = 0; rr < 4; ++rr)
          part[w][gt][quad * 4 + rr][l16] = acc[gt][rr];
    }
    // ---- layer1: bcc = af0 x Wih1 + af1 x Whh1 ----
    {
      f32x4 bcc[4] = {};
#pragma unroll
      for (int kk = 0; kk < 4; ++kk) {
        bcc[0] = __builtin_amdgcn_mfma_f32_16x16x32_f16(af0[kk], wi1r[0][kk], bcc[0], 0, 0, 0);
        bcc[1] = __builtin_amdgcn_mfma_f32_16x16x32_f16(af0[kk], wi1r[1][kk], bcc[1], 0, 0, 0);
        half8 w2 = *(const half8*)(wi1_lds + (0 * 16 + l16) * 1032 + ks + kk * 32 + quad * 8);
        bcc[2] = __builtin_amdgcn_mfma_f32_16x16x32_f16(af0[kk], w2, bcc[2], 0, 0, 0);
        half8 w3 = *(const half8*)(wi1_lds + (1 * 16 + l16) * 1032 + ks + kk * 32 + quad * 8);
        bcc[3] = __builtin_amdgcn_mfma_f32_16x16x32_f16(af0[kk], w3, bcc[3], 0, 0, 0);
      }
#pragma unroll
      for (int kk = 0; kk < 4; ++kk)
#pragma unroll
        for (int gt = 0; gt < 4; ++gt)
          bcc[gt] = __builtin_amdgcn_mfma_f32_16x16x32_f16(af1[kk], wh1[gt][kk], bcc[gt], 0, 0, 0);
#pragma unroll
      for (int gt = 0; gt < 4; ++gt)
#pragma unroll
        for (int rr = 0; rr < 4; ++rr)
          part[w][4 + gt][quad * 4 + rr][l16] = bcc[gt][rr];
    }
    __syncthreads();  // sync#1

    {  // cross-wave K reduction: wave w reduces plane w (8 planes, 8 waves)
#pragma unroll
      for (int rr = 0; rr < 4; ++rr) {
        int m = quad * 4 + rr;
        float sum = part[0][w][m][l16];
#pragma unroll
        for (int w2 = 1; w2 < 8; ++w2) sum += part[w2][w][m][l16];
        red[w][m][l16] = sum;
      }
    }
    __syncthreads();  // sync#2

    if (w < 4) {
      if (i < T_) {  // layer0 finalize, step i
        int m = fm, n = l16;
        float iv = red[0][m][n] + pxi;
        float fv = red[1][m][n] + pxf;
        float gv = red[2][m][n] + pxg;
        float ov = red[3][m][n] + pxo;
        float si = 1.f / (1.f + __expf(-iv));
        float sf = 1.f / (1.f + __expf(-fv));
        float so = 1.f / (1.f + __expf(-ov));
        float ag = fabsf(gv), eg = __expf(-2.f * ag);
        float tg = (1.f - eg) / (1.f + eg);
        tg = (gv < 0.f) ? -tg : tg;
        float c = sf * cs[0][m][n] + si * tg;
        cs[0][m][n] = c;
        float ac = fabsf(c), ec = __expf(-2.f * ac);
        float th = (1.f - ec) / (1.f + ec);
        th = (c < 0.f) ? -th : th;
        float h = so * th;
        unsigned short hu = __builtin_bit_cast(unsigned short, (_Float16)h);
        unsigned other = __shfl_xor((unsigned)hu, 1, 64);
        if ((l16 & 1) == 0) {
          unsigned packed = (unsigned)hu | (other << 16);
          __hip_atomic_store((unsigned*)(h0w + (size_t)(b0 + m) * H_ + u0 + l16), packed,
                             __ATOMIC_RELAXED, __HIP_MEMORY_SCOPE_AGENT);
        }
        if (i == T_ - 1) {
          hn0[(size_t)(b0 + m) * H_ + u0 + n] = h;
          cn0[(size_t)(b0 + m) * H_ + u0 + n] = c;
        }
      }
    } else {
      if (i >= 1) {  // layer1 finalize, step i-1
        int m = fm, n = l16;
        int j = i - 1;
        float iv = red[4][m][n] + b1v[0];
        float fv = red[5][m][n] + b1v[1];
        float gv = red[6][m][n] + b1v[2];
        float ov = red[7][m][n] + b1v[3];
        float si = 1.f / (1.f + __expf(-iv));
        float sf = 1.f / (1.f + __expf(-fv));
        float so = 1.f / (1.f + __expf(-ov));
        float ag = fabsf(gv), eg = __expf(-2.f * ag);
        float tg = (1.f - eg) / (1.f + eg);
        tg = (gv < 0.f) ? -tg : tg;
        float c = sf * cs[1][m][n] + si * tg;
        cs[1][m][n] = c;
        float ac = fabsf(c), ec = __expf(-2.f * ac);
        float th = (1.f - ec) / (1.f + ec);
        th = (c < 0.f) ? -th : th;
        float h = so * th;
        unsigned short hu = __builtin_bit_cast(unsigned short, (_Float16)h);
        unsigned other = __shfl_xor((unsigned)hu, 1, 64);
        if ((l16 & 1) == 0) {
          unsigned packed = (unsigned)hu | (other << 16);
          __hip_atomic_store((unsigned*)(h1w + (size_t)(b0 + m) * H_ + u0 + l16), packed,
                             __ATOMIC_RELAXED, __HIP_MEMORY_SCOPE_AGENT);
        }
        out32[((size_t)(b0 + m) * T_ + j) * H_ + u0 + n] = h;
        if (j == T_ - 1) {
          hn1[(size_t)(b0 + m) * H_ + u0 + n] = h;
          cn1[(size_t)(b0 + m) * H_ + u0 + n] = c;
        }
      }
    }
    __syncthreads();  // drain: compiler emits s_waitcnt vmcnt(0) before s_barrier

    if (i == T_) break;
    unsigned int tgt = 64u * (unsigned)(i + 1);
    if (w == 0) {
      if (lane == 0)
        __hip_atomic_fetch_add(cnt, 1u, __ATOMIC_RELAXED, __HIP_MEMORY_SCOPE_AGENT);
      while (__hip_atomic_load(cnt, __ATOMIC_RELAXED, __HIP_MEMORY_SCOPE_AGENT) < tgt)
        __builtin_amdgcn_s_sleep(1);
      asm volatile("" ::: "memory");  // block hoisting next iteration's loads
      if (lane == 0) __atomic_store_n(&step_flag, i + 1, __ATOMIC_RELEASE);
    } else {
      while (__atomic_load_n(&step_flag, __ATOMIC_ACQUIRE) < i + 1)
        __builtin_amdgcn_s_sleep(1);
    }
  }
}

// ---------------- host ----------------
extern "C" void kernel_launch(void* const* d_in, const int* in_sizes, int n_in,
                              void* d_out, int out_size, void* d_ws, size_t ws_size,
                              hipStream_t stream) {
  (void)in_sizes; (void)n_in; (void)out_size;
  const float* X    = (const float*)d_in[0];
  const float* Wih0 = (const float*)d_in[1];
  const float* bih0 = (const float*)d_in[2];
  const float* Whh0 = (const float*)d_in[3];
  const float* bhh0 = (const float*)d_in[4];
  const float* Wih1 = (const float*)d_in[5];
  const float* bih1 = (const float*)d_in[6];
  const float* Whh1 = (const float*)d_in[7];
  const float* bhh1 = (const float*)d_in[8];
  float* out = (float*)d_out;
  char* ws = (char*)d_ws;

  // ws layout (bytes):
  constexpr size_t SZW = (size_t)G_ * K_ * 2;  // 8 MB per packed weight
  constexpr size_t OFF_B0   = 4 * SZW;
  constexpr size_t OFF_B1   = OFF_B0 + 16384;
  constexpr size_t OFF_CNT  = OFF_B1 + 16384;          // counters (16KB reserved)
  constexpr size_t OFF_HBUF = OFF_CNT + 16384;         // 4 h buffers x 128KB
  constexpr size_t OFF_XG   = OFF_HBUF + 4 * 131072;
  constexpr size_t NEED     = OFF_XG + (size_t)MPROJ * G_ * 2;
  if (ws_size < NEED) return;  // fail visibly rather than corrupt

  _Float16* Wih0h = (_Float16*)(ws + 0 * SZW);
  _Float16* Whh0h = (_Float16*)(ws + 1 * SZW);
  _Float16* Wih1h = (_Float16*)(ws + 2 * SZW);
  _Float16* Whh1h = (_Float16*)(ws + 3 * SZW);
  float* b0s = (float*)(ws + OFF_B0);
  float* b1s = (float*)(ws + OFF_B1);
  unsigned int* cnts = (unsigned int*)(ws + OFF_CNT);
  _Float16* hb = (_Float16*)(ws + OFF_HBUF);
  _Float16* h0a = hb;
  _Float16* h0b = hb + 65536;
  _Float16* h1a = hb + 131072;
  _Float16* h1b = hb + 196608;
  _Float16* xgp = (_Float16*)(ws + OFF_XG);

  // prep: pack weights to fp16, fold biases, zero counters + h buffers
  k_f32_to_f16<<<4096, 256, 0, stream>>>(Wih0, Wih0h, G_ * K_ / 4);
  k_f32_to_f16<<<4096, 256, 0, stream>>>(Whh0, Whh0h, G_ * K_ / 4);
  k_f32_to_f16<<<4096, 256, 0, stream>>>(Wih1, Wih1h, G_ * K_ / 4);
  k_f32_to_f16<<<4096, 256, 0, stream>>>(Whh1, Whh1h, G_ * K_ / 4);
  k_bias<<<16, 256, 0, stream>>>(bih0, bhh0, bih1, bhh1, b0s, b1s);
  k_zero<<<132, 256, 0, stream>>>((uint4*)(ws + OFF_CNT), (int)((16384 + 4 * 131072) / 16));

  const int projGrid = (MPROJ / 128) * (G_ / 128);  // 8192
  k_proj<float><<<dim3(projGrid), dim3(256), 0, stream>>>(X, Wih0h, b0s, xgp);

  {
    const _Float16* a0 = xgp;
    const _Float16* a1 = Whh0h;
    const _Float16* a2 = Wih1h;
    const _Float16* a3 = Whh1h;
    const float* a4 = b1s;
    _Float16* a5 = h0a;
    _Float16* a6 = h0b;
    _Float16* a7 = h1a;
    _Float16* a8 = h1b;
    unsigned int* a9 = cnts;
    float* a10 = out;                               // out1 [B][T][H]
    float* a11 = out + 33554432;                    // h_n[0]
    float* a12 = out + 33554432 + 131072;           // c_n[0]
    float* a13 = out + 33554432 + 65536;            // h_n[1]
    float* a14 = out + 33554432 + 131072 + 65536;   // c_n[1]
    void* args[15] = {&a0, &a1, &a2, &a3, &a4, &a5, &a6, &a7,
                      &a8, &a9, &a10, &a11, &a12, &a13, &a14};
    hipLaunchCooperativeKernel((void*)k_fused, dim3(256), dim3(512), args, 0, stream);
  }
}

// Round 4
// 4953.613 us; speedup vs baseline: 2.0581x; 1.0168x over previous
//
#include <hip/hip_runtime.h>
#include <type_traits>

// ---------------- types ----------------
typedef _Float16 half8 __attribute__((ext_vector_type(8)));
typedef _Float16 half4v __attribute__((ext_vector_type(4)));
typedef float f32x4 __attribute__((ext_vector_type(4)));
typedef unsigned long long u64;

struct U128 { u64 a, b; };

#define B_ 64
#define T_ 512
#define H_ 1024
#define G_ 4096      // 4*H
#define K_ 1024
#define MPROJ (B_ * T_)  // 32768

// ---------------- prep kernels ----------------
__global__ void k_f32_to_f16(const float* __restrict__ s, _Float16* __restrict__ d, int n4) {
  int i = blockIdx.x * 256 + threadIdx.x;
  if (i < n4) {
    float4 v = ((const float4*)s)[i];
    half4v o;
    o[0] = (_Float16)v.x; o[1] = (_Float16)v.y; o[2] = (_Float16)v.z; o[3] = (_Float16)v.w;
    ((half4v*)d)[i] = o;
  }
}

__global__ void k_bias(const float* __restrict__ bi0, const float* __restrict__ bh0,
                       const float* __restrict__ bi1, const float* __restrict__ bh1,
                       float* __restrict__ o0, float* __restrict__ o1) {
  int i = blockIdx.x * 256 + threadIdx.x;
  if (i < G_) { o0[i] = bi0[i] + bh0[i]; o1[i] = bi1[i] + bh1[i]; }
}

__global__ void k_zero(uint4* __restrict__ p, int n) {
  int i = blockIdx.x * 256 + threadIdx.x;
  if (i < n) p[i] = make_uint4(0u, 0u, 0u, 0u);
}

// ---------------- projection GEMM (layer 0 only) ----------------
// C[m][n] = sum_k A[m][k]*Bw[n][k] + bias[n], C stored fp16. M=32768, N=4096, K=1024.
template <typename AT>
__global__ __launch_bounds__(256, 2) void k_proj(const AT* __restrict__ A,
                                                 const _Float16* __restrict__ Bw,
                                                 const float* __restrict__ bias,
                                                 _Float16* __restrict__ C) {
  const int NBN = G_ / 128;  // 32
  int bm = blockIdx.x / NBN;
  int bn = blockIdx.x % NBN;
  __shared__ __align__(16) _Float16 As[128 * 40];
  __shared__ __align__(16) _Float16 Bs[128 * 40];
  int tid = threadIdx.x;
  int lane = tid & 63, wave = tid >> 6;
  int wm = (wave >> 1) * 64, wn = (wave & 1) * 64;
  int quad = lane >> 4, l16 = lane & 15;
  f32x4 acc[4][4] = {};
  int r = tid >> 1;
  int hc = (tid & 1) * 16;
  const AT* aRow = A + (size_t)(bm * 128 + r) * K_ + hc;
  const _Float16* bRow = Bw + (size_t)(bn * 128 + r) * K_ + hc;
  _Float16* aDst = As + r * 40 + hc;
  _Float16* bDst = Bs + r * 40 + hc;

  for (int kt = 0; kt < K_ / 32; ++kt) {
    if constexpr (std::is_same<AT, float>::value) {
      float tmp[16];
      *(float4*)(tmp + 0)  = *(const float4*)(aRow + 0);
      *(float4*)(tmp + 4)  = *(const float4*)(aRow + 4);
      *(float4*)(tmp + 8)  = *(const float4*)(aRow + 8);
      *(float4*)(tmp + 12) = *(const float4*)(aRow + 12);
      half8 h0, h1;
#pragma unroll
      for (int e = 0; e < 8; ++e) { h0[e] = (_Float16)tmp[e]; h1[e] = (_Float16)tmp[e + 8]; }
      *(half8*)(aDst) = h0;
      *(half8*)(aDst + 8) = h1;
    } else {
      *(half8*)(aDst) = *(const half8*)(aRow);
      *(half8*)(aDst + 8) = *(const half8*)(aRow + 8);
    }
    *(half8*)(bDst) = *(const half8*)(bRow);
    *(half8*)(bDst + 8) = *(const half8*)(bRow + 8);
    __syncthreads();
    half8 af[4], bf[4];
#pragma unroll
    for (int i = 0; i < 4; ++i) af[i] = *(const half8*)(As + (wm + i * 16 + l16) * 40 + quad * 8);
#pragma unroll
    for (int j = 0; j < 4; ++j) bf[j] = *(const half8*)(Bs + (wn + j * 16 + l16) * 40 + quad * 8);
#pragma unroll
    for (int i = 0; i < 4; ++i)
#pragma unroll
      for (int j = 0; j < 4; ++j)
        acc[i][j] = __builtin_amdgcn_mfma_f32_16x16x32_f16(af[i], bf[j], acc[i][j], 0, 0, 0);
    __syncthreads();
    aRow += 32;
    bRow += 32;
  }
#pragma unroll
  for (int j = 0; j < 4; ++j) {
    int n = bn * 128 + wn + j * 16 + l16;
    float bv = bias[n];
#pragma unroll
    for (int i = 0; i < 4; ++i) {
      size_t m0 = (size_t)(bm * 128 + wm + i * 16 + quad * 4);
#pragma unroll
      for (int rr = 0; rr < 4; ++rr)
        C[(m0 + rr) * G_ + n] = (_Float16)(acc[i][j][rr] + bv);
    }
  }
}

// ---------------- fused 2-layer persistent recurrence ----------------
// 256 WGs x 512 thr (cooperative), 1 WG/CU. Group g = blockIdx&3 owns batch rows
// [16g,16g+16); WG wid = blockIdx>>2 owns hidden units [16wid,16wid+16), BOTH layers.
// Iteration i: layer0 computes step i (i<T), layer1 computes step i-1 (i>=1).
// One barrier per iteration gates both layers' h exchanges.
//
// Barrier (v5): parallel per-WG flag stores (single-writer, NO atomic RMW).
//  - after sync#3 (vmcnt(0) drained the agent h stores), wave1-lane0 stores
//    flags[g*128+wid] = i+1. 64 independent stores land in parallel at the MALL.
//  - wave0 polls all 64 flags with one coalesced 64-lane load; __all(v>=i+1);
//    then relays via LDS step_flag (waves 1-7 spin on LDS -> minimal MALL traffic).
//  - out1 HBM store is issued AFTER the flag publish: it overlaps the spin instead
//    of sitting inside the drain (only the MALL h-store ack remains on the chain).
__global__ __launch_bounds__(512) void k_fused(
    const _Float16* __restrict__ xg,    // [B*T][4H] fp16 layer0 gates (both biases folded)
    const _Float16* __restrict__ Whh0,  // [4H][H] fp16
    const _Float16* __restrict__ Wih1,  // [4H][H] fp16
    const _Float16* __restrict__ Whh1,  // [4H][H] fp16
    const float* __restrict__ b1,       // [4H] folded layer1 bias
    _Float16* __restrict__ h0a, _Float16* __restrict__ h0b,  // layer0 h ping-pong
    _Float16* __restrict__ h1a, _Float16* __restrict__ h1b,  // layer1 h ping-pong
    unsigned int* flags,                // per-group 64 flags (128-dword stride)
    float* __restrict__ out32,          // d_out: out1 [B][T][H] fp32
    float* __restrict__ hn0, float* __restrict__ cn0,
    float* __restrict__ hn1, float* __restrict__ cn1) {
  int g = blockIdx.x & 3;
  int wid = blockIdx.x >> 2;
  int u0 = wid * 16;
  int b0 = g * 16;
  int tid = threadIdx.x;
  int lane = tid & 63, w = tid >> 6;
  int quad = lane >> 4, l16 = lane & 15;
  unsigned int* gf = flags + (g << 7);

  // planes 0-3: layer0 gates; planes 4-7: layer1 gates. m-stride 18 -> <=2-way banks.
  __shared__ float part[8][8][16][18];   // 73728 B
  __shared__ float red[8][16][18];       // 9216 B
  __shared__ float cs[2][16][16];        // 2048 B  (cell states, both layers)
  __shared__ __align__(16) _Float16 wi1_lds[2 * 16 * 1032];  // 66048 B: Wih1 gates 2,3
  __shared__ int step_flag;
  ((float*)cs)[tid] = 0.f;               // tid<512 covers 512 floats exactly
  if (tid == 0) step_flag = 0;

  // stage Wih1 gates 2-3 rows [u0,u0+16) into LDS (one-time)
  for (int idx = tid; idx < 2 * 16 * (K_ / 8); idx += 512) {
    int gt2 = idx >> 11;          // 0..1
    int r = (idx >> 7) & 15;      // 0..15
    int c = idx & 127;            // 0..127 (half8 chunks)
    half8 v = *(const half8*)(Wih1 + (size_t)((2 + gt2) * H_ + u0 + r) * K_ + c * 8);
    *(half8*)(wi1_lds + (gt2 * 16 + r) * 1032 + c * 8) = v;
  }

  // resident weight fragments: wave w covers K-slice [128w, 128w+128)
  int ks = w * 128;
  half8 wf0[4][4], wh1[4][4], wi1r[2][4];
#pragma unroll
  for (int gt = 0; gt < 4; ++gt)
#pragma unroll
    for (int kk = 0; kk < 4; ++kk) {
      wf0[gt][kk] = *(const half8*)(Whh0 + (size_t)(gt * H_ + u0 + l16) * K_ + ks + kk * 32 + quad * 8);
      wh1[gt][kk] = *(const half8*)(Whh1 + (size_t)(gt * H_ + u0 + l16) * K_ + ks + kk * 32 + quad * 8);
    }
#pragma unroll
  for (int gt = 0; gt < 2; ++gt)
#pragma unroll
    for (int kk = 0; kk < 4; ++kk)
      wi1r[gt][kk] = *(const half8*)(Wih1 + (size_t)(gt * H_ + u0 + l16) * K_ + ks + kk * 32 + quad * 8);

  int fm = (w & 3) * 4 + quad;
  float b1v[4] = {};
  if (w >= 4) {
#pragma unroll
    for (int gt = 0; gt < 4; ++gt) b1v[gt] = b1[gt * H_ + u0 + l16];
  }
  __syncthreads();

  for (int i = 0; i <= T_; ++i) {
    const _Float16* h0r = (i & 1) ? h0b : h0a;
    _Float16* h0w = (i & 1) ? h0a : h0b;
    const _Float16* h1r = (i & 1) ? h1b : h1a;
    _Float16* h1w = (i & 1) ? h1a : h1b;

    // layer0 xg prefetch (this iteration's finalize input) — overlaps h loads
    float pxi = 0.f, pxf = 0.f, pxg = 0.f, pxo = 0.f;
    if (w < 4 && i < T_) {
      const _Float16* xr = xg + ((size_t)(b0 + fm) * T_ + i) * G_ + u0 + l16;
      pxi = (float)xr[0];
      pxf = (float)xr[H_];
      pxg = (float)xr[2 * H_];
      pxo = (float)xr[3 * H_];
    }

    // h0(i-1) fragments (feed L0-hh AND L1-ih) and h1(i-2) fragments (L1-hh)
    half8 af0[4], af1[4];
#pragma unroll
    for (int kk = 0; kk < 4; ++kk) {
      const _Float16* hs = h0r + (size_t)(b0 + l16) * H_ + ks + kk * 32 + quad * 8;
      u64 qlo = __hip_atomic_load((const u64*)hs, __ATOMIC_RELAXED, __HIP_MEMORY_SCOPE_AGENT);
      u64 qhi = __hip_atomic_load(((const u64*)hs) + 1, __ATOMIC_RELAXED, __HIP_MEMORY_SCOPE_AGENT);
      U128 u; u.a = qlo; u.b = qhi;
      af0[kk] = __builtin_bit_cast(half8, u);
    }
#pragma unroll
    for (int kk = 0; kk < 4; ++kk) {
      const _Float16* hs = h1r + (size_t)(b0 + l16) * H_ + ks + kk * 32 + quad * 8;
      u64 qlo = __hip_atomic_load((const u64*)hs, __ATOMIC_RELAXED, __HIP_MEMORY_SCOPE_AGENT);
      u64 qhi = __hip_atomic_load(((const u64*)hs) + 1, __ATOMIC_RELAXED, __HIP_MEMORY_SCOPE_AGENT);
      U128 u; u.a = qlo; u.b = qhi;
      af1[kk] = __builtin_bit_cast(half8, u);
    }

    // ---- layer0: acc = af0 x Whh0 ----
    {
      f32x4 acc[4] = {};
#pragma unroll
      for (int kk = 0; kk < 4; ++kk)
#pragma unroll
        for (int gt = 0; gt < 4; ++gt)
          acc[gt] = __builtin_amdgcn_mfma_f32_16x16x32_f16(af0[kk], wf0[gt][kk], acc[gt], 0, 0, 0);
#pragma unroll
      for (int gt = 0; gt < 4; ++gt)
#pragma unroll
        for (int rr = 0; rr < 4; ++rr)
          part[w][gt][quad * 4 + rr][l16] = acc[gt][rr];
    }
    // ---- layer1: bcc = af0 x Wih1 + af1 x Whh1 ----
    {
      f32x4 bcc[4] = {};
#pragma unroll
      for (int kk = 0; kk < 4; ++kk) {
        bcc[0] = __builtin_amdgcn_mfma_f32_16x16x32_f16(af0[kk], wi1r[0][kk], bcc[0], 0, 0, 0);
        bcc[1] = __builtin_amdgcn_mfma_f32_16x16x32_f16(af0[kk], wi1r[1][kk], bcc[1], 0, 0, 0);
        half8 w2 = *(const half8*)(wi1_lds + (0 * 16 + l16) * 1032 + ks + kk * 32 + quad * 8);
        bcc[2] = __builtin_amdgcn_mfma_f32_16x16x32_f16(af0[kk], w2, bcc[2], 0, 0, 0);
        half8 w3 = *(const half8*)(wi1_lds + (1 * 16 + l16) * 1032 + ks + kk * 32 + quad * 8);
        bcc[3] = __builtin_amdgcn_mfma_f32_16x16x32_f16(af0[kk], w3, bcc[3], 0, 0, 0);
      }
#pragma unroll
      for (int kk = 0; kk < 4; ++kk)
#pragma unroll
        for (int gt = 0; gt < 4; ++gt)
          bcc[gt] = __builtin_amdgcn_mfma_f32_16x16x32_f16(af1[kk], wh1[gt][kk], bcc[gt], 0, 0, 0);
#pragma unroll
      for (int gt = 0; gt < 4; ++gt)
#pragma unroll
        for (int rr = 0; rr < 4; ++rr)
          part[w][4 + gt][quad * 4 + rr][l16] = bcc[gt][rr];
    }
    __syncthreads();  // sync#1

    {  // cross-wave K reduction: wave w reduces plane w (8 planes, 8 waves)
#pragma unroll
      for (int rr = 0; rr < 4; ++rr) {
        int m = quad * 4 + rr;
        float sum = part[0][w][m][l16];
#pragma unroll
        for (int w2 = 1; w2 < 8; ++w2) sum += part[w2][w][m][l16];
        red[w][m][l16] = sum;
      }
    }
    __syncthreads();  // sync#2

    float ph = 0.f;        // deferred out1 value (waves 4-7)
    size_t poidx = 0;
    if (w < 4) {
      if (i < T_) {  // layer0 finalize, step i
        int m = fm, n = l16;
        float iv = red[0][m][n] + pxi;
        float fv = red[1][m][n] + pxf;
        float gv = red[2][m][n] + pxg;
        float ov = red[3][m][n] + pxo;
        float si = 1.f / (1.f + __expf(-iv));
        float sf = 1.f / (1.f + __expf(-fv));
        float so = 1.f / (1.f + __expf(-ov));
        float ag = fabsf(gv), eg = __expf(-2.f * ag);
        float tg = (1.f - eg) / (1.f + eg);
        tg = (gv < 0.f) ? -tg : tg;
        float c = sf * cs[0][m][n] + si * tg;
        cs[0][m][n] = c;
        float ac = fabsf(c), ec = __expf(-2.f * ac);
        float th = (1.f - ec) / (1.f + ec);
        th = (c < 0.f) ? -th : th;
        float h = so * th;
        unsigned short hu = __builtin_bit_cast(unsigned short, (_Float16)h);
        unsigned other = __shfl_xor((unsigned)hu, 1, 64);
        if ((l16 & 1) == 0) {
          unsigned packed = (unsigned)hu | (other << 16);
          __hip_atomic_store((unsigned*)(h0w + (size_t)(b0 + m) * H_ + u0 + l16), packed,
                             __ATOMIC_RELAXED, __HIP_MEMORY_SCOPE_AGENT);
        }
        if (i == T_ - 1) {
          hn0[(size_t)(b0 + m) * H_ + u0 + n] = h;
          cn0[(size_t)(b0 + m) * H_ + u0 + n] = c;
        }
      }
    } else {
      if (i >= 1) {  // layer1 finalize, step i-1
        int m = fm, n = l16;
        int j = i - 1;
        float iv = red[4][m][n] + b1v[0];
        float fv = red[5][m][n] + b1v[1];
        float gv = red[6][m][n] + b1v[2];
        float ov = red[7][m][n] + b1v[3];
        float si = 1.f / (1.f + __expf(-iv));
        float sf = 1.f / (1.f + __expf(-fv));
        float so = 1.f / (1.f + __expf(-ov));
        float ag = fabsf(gv), eg = __expf(-2.f * ag);
        float tg = (1.f - eg) / (1.f + eg);
        tg = (gv < 0.f) ? -tg : tg;
        float c = sf * cs[1][m][n] + si * tg;
        cs[1][m][n] = c;
        float ac = fabsf(c), ec = __expf(-2.f * ac);
        float th = (1.f - ec) / (1.f + ec);
        th = (c < 0.f) ? -th : th;
        float h = so * th;
        unsigned short hu = __builtin_bit_cast(unsigned short, (_Float16)h);
        unsigned other = __shfl_xor((unsigned)hu, 1, 64);
        if ((l16 & 1) == 0) {
          unsigned packed = (unsigned)hu | (other << 16);
          __hip_atomic_store((unsigned*)(h1w + (size_t)(b0 + m) * H_ + u0 + l16), packed,
                             __ATOMIC_RELAXED, __HIP_MEMORY_SCOPE_AGENT);
        }
        // DEFER the out1 HBM store past the publish (off the drain path)
        ph = h;
        poidx = ((size_t)(b0 + m) * T_ + j) * H_ + u0 + n;
        if (j == T_ - 1) {
          hn1[(size_t)(b0 + m) * H_ + u0 + n] = h;
          cn1[(size_t)(b0 + m) * H_ + u0 + n] = c;
        }
      }
    }
    __syncthreads();  // sync#3: vmcnt(0) drain of the agent h stores (only)

    if (i == T_) {
      if (w >= 4) out32[poidx] = ph;  // last deferred store (j = T_-1)
      break;
    }
    // publish: parallel single-writer flag store (no RMW). wave1 does it so
    // wave0's first poll is not queued behind the store in its vmcnt stream.
    if (w == 1 && lane == 0)
      __hip_atomic_store(gf + wid, (unsigned)(i + 1),
                         __ATOMIC_RELAXED, __HIP_MEMORY_SCOPE_AGENT);
    // deferred out1 store: overlaps the spin instead of sitting in the drain
    if (w >= 4 && i >= 1) out32[poidx] = ph;

    unsigned tgt = (unsigned)(i + 1);
    if (w == 0) {
      for (;;) {
        unsigned v = __hip_atomic_load(gf + lane, __ATOMIC_RELAXED, __HIP_MEMORY_SCOPE_AGENT);
        if (__all(v >= tgt)) break;
        __builtin_amdgcn_s_sleep(1);
      }
      asm volatile("" ::: "memory");  // block hoisting next iteration's loads
      if (lane == 0) __atomic_store_n(&step_flag, (int)tgt, __ATOMIC_RELEASE);
    } else {
      while (__atomic_load_n(&step_flag, __ATOMIC_ACQUIRE) < (int)tgt)
        __builtin_amdgcn_s_sleep(1);
      asm volatile("" ::: "memory");
    }
  }
}

// ---------------- host ----------------
extern "C" void kernel_launch(void* const* d_in, const int* in_sizes, int n_in,
                              void* d_out, int out_size, void* d_ws, size_t ws_size,
                              hipStream_t stream) {
  (void)in_sizes; (void)n_in; (void)out_size;
  const float* X    = (const float*)d_in[0];
  const float* Wih0 = (const float*)d_in[1];
  const float* bih0 = (const float*)d_in[2];
  const float* Whh0 = (const float*)d_in[3];
  const float* bhh0 = (const float*)d_in[4];
  const float* Wih1 = (const float*)d_in[5];
  const float* bih1 = (const float*)d_in[6];
  const float* Whh1 = (const float*)d_in[7];
  const float* bhh1 = (const float*)d_in[8];
  float* out = (float*)d_out;
  char* ws = (char*)d_ws;

  // ws layout (bytes):
  constexpr size_t SZW = (size_t)G_ * K_ * 2;  // 8 MB per packed weight
  constexpr size_t OFF_B0   = 4 * SZW;
  constexpr size_t OFF_B1   = OFF_B0 + 16384;
  constexpr size_t OFF_CNT  = OFF_B1 + 16384;          // flags (16KB reserved)
  constexpr size_t OFF_HBUF = OFF_CNT + 16384;         // 4 h buffers x 128KB
  constexpr size_t OFF_XG   = OFF_HBUF + 4 * 131072;
  constexpr size_t NEED     = OFF_XG + (size_t)MPROJ * G_ * 2;
  if (ws_size < NEED) return;  // fail visibly rather than corrupt

  _Float16* Wih0h = (_Float16*)(ws + 0 * SZW);
  _Float16* Whh0h = (_Float16*)(ws + 1 * SZW);
  _Float16* Wih1h = (_Float16*)(ws + 2 * SZW);
  _Float16* Whh1h = (_Float16*)(ws + 3 * SZW);
  float* b0s = (float*)(ws + OFF_B0);
  float* b1s = (float*)(ws + OFF_B1);
  unsigned int* flgs = (unsigned int*)(ws + OFF_CNT);
  _Float16* hb = (_Float16*)(ws + OFF_HBUF);
  _Float16* h0a = hb;
  _Float16* h0b = hb + 65536;
  _Float16* h1a = hb + 131072;
  _Float16* h1b = hb + 196608;
  _Float16* xgp = (_Float16*)(ws + OFF_XG);

  // prep: pack weights to fp16, fold biases, zero flags + h buffers
  k_f32_to_f16<<<4096, 256, 0, stream>>>(Wih0, Wih0h, G_ * K_ / 4);
  k_f32_to_f16<<<4096, 256, 0, stream>>>(Whh0, Whh0h, G_ * K_ / 4);
  k_f32_to_f16<<<4096, 256, 0, stream>>>(Wih1, Wih1h, G_ * K_ / 4);
  k_f32_to_f16<<<4096, 256, 0, stream>>>(Whh1, Whh1h, G_ * K_ / 4);
  k_bias<<<16, 256, 0, stream>>>(bih0, bhh0, bih1, bhh1, b0s, b1s);
  k_zero<<<132, 256, 0, stream>>>((uint4*)(ws + OFF_CNT), (int)((16384 + 4 * 131072) / 16));

  const int projGrid = (MPROJ / 128) * (G_ / 128);  // 8192
  k_proj<float><<<dim3(projGrid), dim3(256), 0, stream>>>(X, Wih0h, b0s, xgp);

  {
    const _Float16* a0 = xgp;
    const _Float16* a1 = Whh0h;
    const _Float16* a2 = Wih1h;
    const _Float16* a3 = Whh1h;
    const float* a4 = b1s;
    _Float16* a5 = h0a;
    _Float16* a6 = h0b;
    _Float16* a7 = h1a;
    _Float16* a8 = h1b;
    unsigned int* a9 = flgs;
    float* a10 = out;                               // out1 [B][T][H]
    float* a11 = out + 33554432;                    // h_n[0]
    float* a12 = out + 33554432 + 131072;           // c_n[0]
    float* a13 = out + 33554432 + 65536;            // h_n[1]
    float* a14 = out + 33554432 + 131072 + 65536;   // c_n[1]
    void* args[15] = {&a0, &a1, &a2, &a3, &a4, &a5, &a6, &a7,
                      &a8, &a9, &a10, &a11, &a12, &a13, &a14};
    hipLaunchCooperativeKernel((void*)k_fused, dim3(256), dim3(512), args, 0, stream);
  }
}